// Round 7
// baseline (149.964 us; speedup 1.0000x reference)
//
#include <hip/hip_runtime.h>
#include <math.h>

// ---------------------------------------------------------------------------
// QCNN 8-qubit statevector, v7: multilinear-tensor factorization.
// v6 + fix: qcnn_eval_grid has NO divergent early-exit. 6561 is not a
// multiple of 4 elems/wave; the old partial-wave exit let the compiler sink
// the pp (param) loads past the branch, so exited lanes held garbage and
// v_readlane (EXEC-ignoring) fed NaN into E[6560] -> butterfly spread it to
// ALL coefficients -> all-NaN output. Now every lane stays active; only the
// final store is predicated.
//   g_par[256]  : fused gate params (v4 layout; MLP at 208..248)
//   g_E[13122]  : E3[6561], E7[6561] grid evals
//   g_T[13608]  : T3 (81x84), T7 (81x84) coefficient tensors
// ---------------------------------------------------------------------------

__device__ float g_par[256];
__device__ float g_E[13122];
__device__ __align__(16) float g_T[13608];

struct c32 { float x, y; };
__device__ __forceinline__ c32 cmul(c32 a, c32 b){ return c32{a.x*b.x - a.y*b.y, a.x*b.y + a.y*b.x}; }
__device__ __forceinline__ c32 cadd(c32 a, c32 b){ return c32{a.x+b.x, a.y+b.y}; }
__device__ __forceinline__ c32 csel(bool c, c32 a, c32 b){ return c32{c?a.x:b.x, c?a.y:b.y}; }

struct PP { float a, b, c, d; };

__device__ __forceinline__ float pget(int i, PP pp) {
    float s = (i < 64) ? pp.a : (i < 128) ? pp.b : (i < 192) ? pp.c : pp.d;
    return __uint_as_float(__builtin_amdgcn_readlane(__float_as_uint(s), i & 63));
}
#define P(I) pget((I), pp)

template<int M>
__device__ __forceinline__ float sx(float v) {
    if constexpr (M == 1) {        // quad_perm [1,0,3,2]
        return __int_as_float(__builtin_amdgcn_update_dpp(
            __float_as_int(v), __float_as_int(v), 0xB1, 0xF, 0xF, false));
    } else if constexpr (M == 2) { // quad_perm [2,3,0,1]
        return __int_as_float(__builtin_amdgcn_update_dpp(
            __float_as_int(v), __float_as_int(v), 0x4E, 0xF, 0xF, false));
    } else if constexpr (M == 4) {
        return __int_as_float(__builtin_amdgcn_ds_swizzle(__float_as_int(v), 0x101F));
    } else {                       // M == 8
        return __int_as_float(__builtin_amdgcn_ds_swizzle(__float_as_int(v), 0x201F));
    }
}

// ---- v4 fused-conv machinery (verbatim, verified) ----
template<int RM, int LQ, bool KEEPD, int BASE>
__device__ __forceinline__ void conv_A(c32 s[16], int sub, PP pp) {
    #pragma unroll
    for (int r = 0; r < 16; ++r) if (r & RM) { s[r].x = sx<LQ>(s[r].x); s[r].y = sx<LQ>(s[r].y); }
    const bool cb = (sub & LQ) != 0;
    const c32 M00 = csel(cb, c32{P(BASE+8),P(BASE+9)},   c32{P(BASE+0),P(BASE+1)});
    const c32 M01 = csel(cb, c32{P(BASE+10),P(BASE+11)}, c32{P(BASE+2),P(BASE+3)});
    const c32 M10 = csel(cb, c32{P(BASE+12),P(BASE+13)}, c32{P(BASE+4),P(BASE+5)});
    const c32 M11 = csel(cb, c32{P(BASE+14),P(BASE+15)}, c32{P(BASE+6),P(BASE+7)});
    #pragma unroll
    for (int r = 0; r < 16; ++r) if (!(r & RM)) {
        c32 lo = s[r], hi = s[r|RM];
        s[r]    = cadd(cmul(M00,lo), cmul(M01,hi));
        s[r|RM] = cadd(cmul(M10,lo), cmul(M11,hi));
    }
    if constexpr (KEEPD) {
        #pragma unroll
        for (int r = 0; r < 16; ++r) if (r & RM) { s[r].x = sx<LQ>(s[r].x); s[r].y = sx<LQ>(s[r].y); }
    }
}

template<int RM, int LQ, int BASE>
__device__ __forceinline__ void conv_B(c32 s[16], int sub, PP pp) {
    const bool cb = (sub & LQ) != 0;
    #pragma unroll
    for (int r = 0; r < 16; ++r) if (!(r & RM)) {
        c32 lo = s[r], hi = s[r|RM];
        s[r]    = csel(cb, hi, lo);
        s[r|RM] = csel(cb, lo, hi);
    }
    const c32 RS0 = csel(cb, c32{P(BASE+6),P(BASE+7)},   c32{P(BASE+0),P(BASE+1)});
    const c32 RP0 = csel(cb, c32{P(BASE+4),P(BASE+5)},   c32{P(BASE+2),P(BASE+3)});
    const c32 RS1 = csel(cb, c32{P(BASE+14),P(BASE+15)}, c32{P(BASE+8),P(BASE+9)});
    const c32 RP1 = csel(cb, c32{P(BASE+12),P(BASE+13)}, c32{P(BASE+10),P(BASE+11)});
    #pragma unroll
    for (int r = 0; r < 16; ++r) {
        c32 pt{ sx<LQ>(s[r].x), sx<LQ>(s[r].y) };
        const c32 RS = (r & RM) ? RS1 : RS0;
        const c32 RP = (r & RM) ? RP1 : RP0;
        s[r] = cadd(cmul(RS, s[r]), cmul(RP, pt));
    }
}

template<int CM, int TM, bool KEEPD, int BASE>
__device__ __forceinline__ void conv_RR(c32 s[16], PP pp) {
    c32 m[2][2][2];
    #pragma unroll
    for (int q = 0; q < 2; ++q)
      #pragma unroll
      for (int i = 0; i < 2; ++i)
        #pragma unroll
        for (int j = 0; j < 2; ++j)
          m[q][i][j] = c32{ P(BASE + q*8 + i*4 + j*2), P(BASE + q*8 + i*4 + j*2 + 1) };
    #pragma unroll
    for (int r = 0; r < 16; ++r) if ((r & TM) && !(r & CM)) { c32 t = s[r]; s[r] = s[r|CM]; s[r|CM] = t; }
    #pragma unroll
    for (int r = 0; r < 16; ++r) if (!(r & TM)) {
        const int q = (r & CM) ? 1 : 0;
        c32 lo = s[r], hi = s[r|TM];
        s[r]    = cadd(cmul(m[q][0][0],lo), cmul(m[q][0][1],hi));
        s[r|TM] = cadd(cmul(m[q][1][0],lo), cmul(m[q][1][1],hi));
    }
    if constexpr (KEEPD) {
        #pragma unroll
        for (int r = 0; r < 16; ++r) if ((r & TM) && !(r & CM)) { c32 t = s[r]; s[r] = s[r|CM]; s[r|CM] = t; }
    }
}

template<int RM, int BASE>
__device__ __forceinline__ void pool_plain(c32 s[16], PP pp) {
    const c32 V00{P(BASE+0),P(BASE+1)}, V01{P(BASE+2),P(BASE+3)};
    const c32 V10{P(BASE+4),P(BASE+5)}, V11{P(BASE+6),P(BASE+7)};
    #pragma unroll
    for (int r = 0; r < 16; ++r) if (!(r & RM)) {
        c32 lo = s[r], hi = s[r|RM];
        s[r]    = cadd(cmul(V00,lo), cmul(V01,hi));
        s[r|RM] = cadd(cmul(V10,lo), cmul(V11,hi));
    }
}
template<int RM, int LQ, int BASE>
__device__ __forceinline__ void pool_lanec(c32 s[16], int sub, PP pp) {
    const bool cb = (sub & LQ) != 0;
    const c32 E00 = csel(cb, c32{P(BASE+2),P(BASE+3)}, c32{P(BASE+0),P(BASE+1)});
    const c32 E01 = csel(cb, c32{P(BASE+0),P(BASE+1)}, c32{P(BASE+2),P(BASE+3)});
    const c32 E10 = csel(cb, c32{P(BASE+6),P(BASE+7)}, c32{P(BASE+4),P(BASE+5)});
    const c32 E11 = csel(cb, c32{P(BASE+4),P(BASE+5)}, c32{P(BASE+6),P(BASE+7)});
    #pragma unroll
    for (int r = 0; r < 16; ++r) if (!(r & RM)) {
        c32 lo = s[r], hi = s[r|RM];
        s[r]    = cadd(cmul(E00,lo), cmul(E01,hi));
        s[r|RM] = cadd(cmul(E10,lo), cmul(E11,hi));
    }
}
template<int RM, int CRM, int BASE>
__device__ __forceinline__ void pool_regc(c32 s[16], PP pp) {
    const c32 V00{P(BASE+0),P(BASE+1)}, V01{P(BASE+2),P(BASE+3)};
    const c32 V10{P(BASE+4),P(BASE+5)}, V11{P(BASE+6),P(BASE+7)};
    #pragma unroll
    for (int r = 0; r < 16; ++r) if (!(r & RM)) {
        const bool swp = (r & CRM) != 0;
        const c32 A = swp ? V01 : V00, Bm = swp ? V00 : V01;
        const c32 C = swp ? V11 : V10, D  = swp ? V10 : V11;
        c32 lo = s[r], hi = s[r|RM];
        s[r]    = cadd(cmul(A,lo),  cmul(Bm,hi));
        s[r|RM] = cadd(cmul(C,lo),  cmul(D,hi));
    }
}

__device__ __forceinline__ float tanh_fast(float x) {
    float e = __expf(2.f * x);
    return (e - 1.f) / (e + 1.f);
}

// ---- S0: fused gate-parameter setup (writes g_par) ----
__global__ void qcnn_setup(const float* __restrict__ rz,  const float* __restrict__ ry,
                           const float* __restrict__ ry2, const float* __restrict__ pool,
                           const float* __restrict__ W1,  const float* __restrict__ b1,
                           const float* __restrict__ W2,  const float* __restrict__ b2) {
    if (threadIdx.x != 0 || blockIdx.x != 0) return;
    float* ws = g_par;
    const bool hasD[10] = {true,true,true,true,false,false,false,true,true,false};
    for (int cc = 0; cc < 10; ++cc) {
        float tz = rz[cc], ta = ry[cc], tb = ry2[cc];
        float cz = cosf(0.5f*tz), sz = sinf(0.5f*tz);
        float cp = cosf(0.5f*(ta+tb)), sp = sinf(0.5f*(ta+tb));
        float cm = cosf(0.5f*(ta-tb)), sm = sinf(0.5f*(ta-tb));
        float A0[2][2] = {{cp,-sp},{sp,cp}};
        float A1[2][2] = {{sm,cm},{cm,-sm}};
        float* o = ws + 16*cc;
        for (int which = 0; which < 2; ++which) {
            float px = cz, py = which ? sz : -sz;
            for (int row = 0; row < 2; ++row)
              for (int col = 0; col < 2; ++col) {
                float ex = which ? A1[row][col] : A0[row][col], ey = 0.f;
                if (hasD[cc] && col == 1) { ey = -ex; ex = 0.f; }
                o[which*8 + row*4 + col*2 + 0] = px*ex - py*ey;
                o[which*8 + row*4 + col*2 + 1] = px*ey + py*ex;
            }
        }
    }
    const bool hasS[6] = {true,true,true,false,true,false};
    for (int pc = 0; pc < 6; ++pc) {
        float th = pool[3*pc], ph = pool[3*pc+1], la = pool[3*pc+2];
        float ct = cosf(0.5f*th), st = sinf(0.5f*th);
        float u[2][2][2] = {
            {{ct, 0.f},           {-cosf(la)*st, -sinf(la)*st}},
            {{cosf(ph)*st, sinf(ph)*st}, {cosf(ph+la)*ct, sinf(ph+la)*ct}}};
        if (hasS[pc]) {
            for (int row = 0; row < 2; ++row) {
                float xx = u[row][1][0], yy = u[row][1][1];
                u[row][1][0] = -yy; u[row][1][1] = xx;
            }
        }
        float* o = ws + 160 + 8*pc;
        for (int row = 0; row < 2; ++row) for (int col = 0; col < 2; ++col) {
            o[row*4+col*2+0] = u[row][col][0];
            o[row*4+col*2+1] = u[row][col][1];
        }
    }
    for (int i = 0; i < 20; ++i) ws[208+i] = W1[i];
    for (int i = 0; i < 10; ++i) { ws[228+i] = b1[i]; ws[238+i] = W2[i]; }
    ws[248] = b2[0];
}

// ---- S1: evaluate e3/e7 on the 3^8 grid. NO divergent exit (see header) ----
__launch_bounds__(256)
__global__ void qcnn_eval_grid() {
    const int lane = threadIdx.x & 63;
    const int sub  = lane & 15;
    int i3 = lane + 192; if (i3 > 248) i3 = 248;
    PP pp{ g_par[lane], g_par[lane+64], g_par[lane+128], g_par[i3] };
    const int gwave = (blockIdx.x * blockDim.x + threadIdx.x) >> 6;
    const int b = gwave * 4 + (lane >> 4);   // b in [0, 6576); all lanes run

    // grid angles x in {0, 2pi/3, -2pi/3} -> half-angle trig is constant
    const float H = 0.8660254037844386f;
    float cw[8], sw_[8];
    int rr = b;
    #pragma unroll
    for (int w = 0; w < 8; ++w) {
        int t = rr % 3; rr /= 3;
        cw[w]  = (t == 0) ? 1.f : 0.5f;
        sw_[w] = (t == 0) ? 0.f : ((t == 1) ? H : -H);
    }

    float a = ((sub & 8) ? sw_[0] : cw[0]);
    a *= (sub & 1) ? sw_[2] : cw[2];
    a *= (sub & 2) ? sw_[4] : cw[4];
    a *= (sub & 4) ? sw_[6] : cw[6];

    c32 s[16];
    float a13[4] = {cw[1]*cw[3], sw_[1]*cw[3], cw[1]*sw_[3], sw_[1]*sw_[3]};
    float a57[4] = {cw[5]*cw[7], sw_[5]*cw[7], cw[5]*sw_[7], sw_[5]*sw_[7]};
    #pragma unroll
    for (int r = 0; r < 16; ++r) s[r] = c32{ a * a13[r & 3] * a57[r >> 2], 0.f };

    conv_A<1, 8, false,  0>(s, sub, pp);
    conv_A<2, 1, true,  16>(s, sub, pp);
    conv_A<4, 2, true,  32>(s, sub, pp);
    conv_A<8, 4, true,  48>(s, sub, pp);
    conv_B<1, 1, 64>(s, sub, pp);
    conv_B<2, 2, 80>(s, sub, pp);
    conv_B<4, 4, 96>(s, sub, pp);
    pool_lanec<1, 1, 160>(s, sub, pp);
    pool_lanec<2, 2, 168>(s, sub, pp);
    pool_lanec<4, 4, 176>(s, sub, pp);
    pool_plain<8, 184>(s, pp);
    conv_RR<1, 2, false, 112>(s, pp);
    conv_RR<4, 8, true,  128>(s, pp);
    conv_RR<2, 4, false, 144>(s, pp);
    pool_regc<2, 4, 192>(s, pp);
    pool_plain<8, 200>(s, pp);

    float e3 = 0.f, e7 = 0.f;
    #pragma unroll
    for (int r = 0; r < 16; ++r) {
        float p = s[r].x*s[r].x + s[r].y*s[r].y;
        e3 += (r & 2) ? -p : p;
        e7 += (r & 8) ? -p : p;
    }
    e3 += sx<1>(e3); e3 += sx<2>(e3); e3 += sx<4>(e3); e3 += sx<8>(e3);
    e7 += sx<1>(e7); e7 += sx<2>(e7); e7 += sx<4>(e7); e7 += sx<8>(e7);

    if (sub == 0 && b < 6561) { g_E[b] = e3; g_E[6561 + b] = e7; }
}

// ---- S2: inverse-Vandermonde per axis, emit T3/T7 [81][84] ----
__global__ void qcnn_transform() {
    __shared__ float E[13122];
    const int tid = threadIdx.x;
    for (int i = tid; i < 13122; i += 256) E[i] = g_E[i];
    __syncthreads();
    int s = 1;
    for (int w = 0; w < 8; ++w) {
        for (int gg = tid; gg < 4374; gg += 256) {
            int obs = (gg >= 2187) ? 1 : 0;
            int g = gg - obs * 2187;
            int base = (g / s) * (3 * s) + (g % s) + obs * 6561;
            float a = E[base], b = E[base + s], c = E[base + 2 * s];
            E[base]         = (a + b + c) * 0.3333333333333333f;
            E[base + s]     = (2.f * a - b - c) * 0.3333333333333333f;
            E[base + 2 * s] = (b - c) * 0.5773502691896258f;
        }
        __syncthreads();
        s *= 3;
    }
    // T[j][k]: coeff at m = j + 81*k   (j = qubits 0-3, k = qubits 4-7)
    for (int i = tid; i < 6804; i += 256) {
        int j = i / 84, k = i - j * 84;
        g_T[i]        = (k < 81) ? E[j + 81 * k] : 0.f;
        g_T[6804 + i] = (k < 81) ? E[6561 + j + 81 * k] : 0.f;
    }
}

// ---- M: per-element multilinear contraction + MLP ----
__launch_bounds__(128)
__global__ void qcnn_apply(const float* __restrict__ x, float* __restrict__ out, int B) {
    __shared__ __align__(16) float Tl[13608];
    {
        float4* Td = reinterpret_cast<float4*>(Tl);
        const float4* Ts = reinterpret_cast<const float4*>(g_T);
        for (int i = threadIdx.x; i < 3402; i += 128) Td[i] = Ts[i];
    }
    __syncthreads();
    const int e = blockIdx.x * 128 + threadIdx.x;
    if (e >= B) return;

    const float4 xv0 = *reinterpret_cast<const float4*>(x + e*8);
    const float4 xv1 = *reinterpret_cast<const float4*>(x + e*8 + 4);
    float C0 = __cosf(xv0.x), S0 = __sinf(xv0.x);
    float C1 = __cosf(xv0.y), S1 = __sinf(xv0.y);
    float C2 = __cosf(xv0.z), S2 = __sinf(xv0.z);
    float C3 = __cosf(xv0.w), S3 = __sinf(xv0.w);
    float C4 = __cosf(xv1.x), S4 = __sinf(xv1.x);
    float C5 = __cosf(xv1.y), S5 = __sinf(xv1.y);
    float C6 = __cosf(xv1.z), S6 = __sinf(xv1.z);
    float C7 = __cosf(xv1.w), S7 = __sinf(xv1.w);

    float g10[9] = {1.f, C0, S0, C1, C1*C0, C1*S0, S1, S1*C0, S1*S0};
    float l9[9]  = {1.f, C4, S4, C5, C5*C4, C5*S4, S5, S5*C4, S5*S4};
    float l27[27];
    #pragma unroll
    for (int a2 = 0; a2 < 9; ++a2) { l27[a2] = l9[a2]; l27[9+a2] = C6*l9[a2]; l27[18+a2] = S6*l9[a2]; }
    float v[84];
    #pragma unroll
    for (int a3 = 0; a3 < 27; ++a3) { v[a3] = l27[a3]; v[27+a3] = C7*l27[a3]; v[54+a3] = S7*l27[a3]; }
    v[81] = 0.f; v[82] = 0.f; v[83] = 0.f;

    const float4* T4 = reinterpret_cast<const float4*>(Tl);
    float e3 = 0.f, e7 = 0.f;
    int rowf4 = 0;
    for (int t3 = 0; t3 < 3; ++t3) {
        float g3v = (t3 == 0) ? 1.f : ((t3 == 1) ? C3 : S3);
        for (int t2 = 0; t2 < 3; ++t2) {
            float g2v = (t2 == 0) ? 1.f : ((t2 == 1) ? C2 : S2);
            float u32 = g3v * g2v;
            #pragma unroll
            for (int jj = 0; jj < 9; ++jj) {
                float w3a = 0.f, w3b = 0.f, w7a = 0.f, w7b = 0.f;
                #pragma unroll
                for (int c = 0; c < 21; ++c) {
                    float4 a3v = T4[rowf4 + jj*21 + c];
                    float4 a7v = T4[rowf4 + jj*21 + c + 1701];
                    if (c & 1) {
                        w3b = fmaf(a3v.x, v[4*c+0], w3b); w3b = fmaf(a3v.y, v[4*c+1], w3b);
                        w3b = fmaf(a3v.z, v[4*c+2], w3b); w3b = fmaf(a3v.w, v[4*c+3], w3b);
                        w7b = fmaf(a7v.x, v[4*c+0], w7b); w7b = fmaf(a7v.y, v[4*c+1], w7b);
                        w7b = fmaf(a7v.z, v[4*c+2], w7b); w7b = fmaf(a7v.w, v[4*c+3], w7b);
                    } else {
                        w3a = fmaf(a3v.x, v[4*c+0], w3a); w3a = fmaf(a3v.y, v[4*c+1], w3a);
                        w3a = fmaf(a3v.z, v[4*c+2], w3a); w3a = fmaf(a3v.w, v[4*c+3], w3a);
                        w7a = fmaf(a7v.x, v[4*c+0], w7a); w7a = fmaf(a7v.y, v[4*c+1], w7a);
                        w7a = fmaf(a7v.z, v[4*c+2], w7a); w7a = fmaf(a7v.w, v[4*c+3], w7a);
                    }
                }
                float uj = u32 * g10[jj];
                e3 = fmaf(uj, w3a + w3b, e3);
                e7 = fmaf(uj, w7a + w7b, e7);
            }
            rowf4 += 189;   // 9 rows * 21 float4
        }
    }

    float z = g_par[248];
    #pragma unroll
    for (int i = 0; i < 10; ++i) {
        float h = tanh_fast(g_par[208+2*i]*e3 + g_par[209+2*i]*e7 + g_par[228+i]);
        z += g_par[238+i]*h;
    }
    out[e] = 1.f / (1.f + __expf(-z));
}

extern "C" void kernel_launch(void* const* d_in, const int* in_sizes, int n_in,
                              void* d_out, int out_size, void* d_ws, size_t ws_size,
                              hipStream_t stream) {
    const float* x       = (const float*)d_in[0];
    const float* conv_rz = (const float*)d_in[1];
    const float* conv_ry = (const float*)d_in[2];
    const float* conv_ry2= (const float*)d_in[3];
    const float* pool    = (const float*)d_in[4];
    const float* W1      = (const float*)d_in[5];
    const float* b1      = (const float*)d_in[6];
    const float* W2      = (const float*)d_in[7];
    const float* b2      = (const float*)d_in[8];
    float* out = (float*)d_out;
    (void)d_ws; (void)ws_size;

    int B = in_sizes[0] / 8;

    qcnn_setup<<<1, 1, 0, stream>>>(conv_rz, conv_ry, conv_ry2, pool, W1, b1, W2, b2);
    qcnn_eval_grid<<<411, 256, 0, stream>>>();
    qcnn_transform<<<1, 256, 0, stream>>>();
    qcnn_apply<<<(B + 127) / 128, 128, 0, stream>>>(x, out, B);
}

// Round 8
// 70.156 us; speedup vs baseline: 2.1376x; 2.1376x over previous
//
#include <hip/hip_runtime.h>
#include <math.h>

// ---------------------------------------------------------------------------
// QCNN 8-qubit statevector, v8: multilinear tensor factorization.
// v7 pipeline, with qcnn_apply restructured:
//   - E=4 elements per thread (T read once per 4 elements -> LDS traffic /4)
//   - basis factorized v = p(a;q4,q5) (x) q(b;q6,q7)  (18 regs, not 84)
//   - 12 roles = tensor(2) x t3(3) x b-half(2), one role per wave,
//     768-thread blocks = 256 elements; partials combined via LDS.
//   - T in padded LDS layout [tensor][j=81][b=9][a pad 12] (16B-aligned)
// g_par[256] fused params; g_E[13122] grid evals; g_T[17496] padded tensors.
// ---------------------------------------------------------------------------

__device__ float g_par[256];
__device__ float g_E[13122];
__device__ __align__(16) float g_T[17496];

struct c32 { float x, y; };
__device__ __forceinline__ c32 cmul(c32 a, c32 b){ return c32{a.x*b.x - a.y*b.y, a.x*b.y + a.y*b.x}; }
__device__ __forceinline__ c32 cadd(c32 a, c32 b){ return c32{a.x+b.x, a.y+b.y}; }
__device__ __forceinline__ c32 csel(bool c, c32 a, c32 b){ return c32{c?a.x:b.x, c?a.y:b.y}; }

struct PP { float a, b, c, d; };

__device__ __forceinline__ float pget(int i, PP pp) {
    float s = (i < 64) ? pp.a : (i < 128) ? pp.b : (i < 192) ? pp.c : pp.d;
    return __uint_as_float(__builtin_amdgcn_readlane(__float_as_uint(s), i & 63));
}
#define P(I) pget((I), pp)

template<int M>
__device__ __forceinline__ float sx(float v) {
    if constexpr (M == 1) {
        return __int_as_float(__builtin_amdgcn_update_dpp(
            __float_as_int(v), __float_as_int(v), 0xB1, 0xF, 0xF, false));
    } else if constexpr (M == 2) {
        return __int_as_float(__builtin_amdgcn_update_dpp(
            __float_as_int(v), __float_as_int(v), 0x4E, 0xF, 0xF, false));
    } else if constexpr (M == 4) {
        return __int_as_float(__builtin_amdgcn_ds_swizzle(__float_as_int(v), 0x101F));
    } else {
        return __int_as_float(__builtin_amdgcn_ds_swizzle(__float_as_int(v), 0x201F));
    }
}

// ---- v4 fused-conv machinery (verbatim, verified) ----
template<int RM, int LQ, bool KEEPD, int BASE>
__device__ __forceinline__ void conv_A(c32 s[16], int sub, PP pp) {
    #pragma unroll
    for (int r = 0; r < 16; ++r) if (r & RM) { s[r].x = sx<LQ>(s[r].x); s[r].y = sx<LQ>(s[r].y); }
    const bool cb = (sub & LQ) != 0;
    const c32 M00 = csel(cb, c32{P(BASE+8),P(BASE+9)},   c32{P(BASE+0),P(BASE+1)});
    const c32 M01 = csel(cb, c32{P(BASE+10),P(BASE+11)}, c32{P(BASE+2),P(BASE+3)});
    const c32 M10 = csel(cb, c32{P(BASE+12),P(BASE+13)}, c32{P(BASE+4),P(BASE+5)});
    const c32 M11 = csel(cb, c32{P(BASE+14),P(BASE+15)}, c32{P(BASE+6),P(BASE+7)});
    #pragma unroll
    for (int r = 0; r < 16; ++r) if (!(r & RM)) {
        c32 lo = s[r], hi = s[r|RM];
        s[r]    = cadd(cmul(M00,lo), cmul(M01,hi));
        s[r|RM] = cadd(cmul(M10,lo), cmul(M11,hi));
    }
    if constexpr (KEEPD) {
        #pragma unroll
        for (int r = 0; r < 16; ++r) if (r & RM) { s[r].x = sx<LQ>(s[r].x); s[r].y = sx<LQ>(s[r].y); }
    }
}

template<int RM, int LQ, int BASE>
__device__ __forceinline__ void conv_B(c32 s[16], int sub, PP pp) {
    const bool cb = (sub & LQ) != 0;
    #pragma unroll
    for (int r = 0; r < 16; ++r) if (!(r & RM)) {
        c32 lo = s[r], hi = s[r|RM];
        s[r]    = csel(cb, hi, lo);
        s[r|RM] = csel(cb, lo, hi);
    }
    const c32 RS0 = csel(cb, c32{P(BASE+6),P(BASE+7)},   c32{P(BASE+0),P(BASE+1)});
    const c32 RP0 = csel(cb, c32{P(BASE+4),P(BASE+5)},   c32{P(BASE+2),P(BASE+3)});
    const c32 RS1 = csel(cb, c32{P(BASE+14),P(BASE+15)}, c32{P(BASE+8),P(BASE+9)});
    const c32 RP1 = csel(cb, c32{P(BASE+12),P(BASE+13)}, c32{P(BASE+10),P(BASE+11)});
    #pragma unroll
    for (int r = 0; r < 16; ++r) {
        c32 pt{ sx<LQ>(s[r].x), sx<LQ>(s[r].y) };
        const c32 RS = (r & RM) ? RS1 : RS0;
        const c32 RP = (r & RM) ? RP1 : RP0;
        s[r] = cadd(cmul(RS, s[r]), cmul(RP, pt));
    }
}

template<int CM, int TM, bool KEEPD, int BASE>
__device__ __forceinline__ void conv_RR(c32 s[16], PP pp) {
    c32 m[2][2][2];
    #pragma unroll
    for (int q = 0; q < 2; ++q)
      #pragma unroll
      for (int i = 0; i < 2; ++i)
        #pragma unroll
        for (int j = 0; j < 2; ++j)
          m[q][i][j] = c32{ P(BASE + q*8 + i*4 + j*2), P(BASE + q*8 + i*4 + j*2 + 1) };
    #pragma unroll
    for (int r = 0; r < 16; ++r) if ((r & TM) && !(r & CM)) { c32 t = s[r]; s[r] = s[r|CM]; s[r|CM] = t; }
    #pragma unroll
    for (int r = 0; r < 16; ++r) if (!(r & TM)) {
        const int q = (r & CM) ? 1 : 0;
        c32 lo = s[r], hi = s[r|TM];
        s[r]    = cadd(cmul(m[q][0][0],lo), cmul(m[q][0][1],hi));
        s[r|TM] = cadd(cmul(m[q][1][0],lo), cmul(m[q][1][1],hi));
    }
    if constexpr (KEEPD) {
        #pragma unroll
        for (int r = 0; r < 16; ++r) if ((r & TM) && !(r & CM)) { c32 t = s[r]; s[r] = s[r|CM]; s[r|CM] = t; }
    }
}

template<int RM, int BASE>
__device__ __forceinline__ void pool_plain(c32 s[16], PP pp) {
    const c32 V00{P(BASE+0),P(BASE+1)}, V01{P(BASE+2),P(BASE+3)};
    const c32 V10{P(BASE+4),P(BASE+5)}, V11{P(BASE+6),P(BASE+7)};
    #pragma unroll
    for (int r = 0; r < 16; ++r) if (!(r & RM)) {
        c32 lo = s[r], hi = s[r|RM];
        s[r]    = cadd(cmul(V00,lo), cmul(V01,hi));
        s[r|RM] = cadd(cmul(V10,lo), cmul(V11,hi));
    }
}
template<int RM, int LQ, int BASE>
__device__ __forceinline__ void pool_lanec(c32 s[16], int sub, PP pp) {
    const bool cb = (sub & LQ) != 0;
    const c32 E00 = csel(cb, c32{P(BASE+2),P(BASE+3)}, c32{P(BASE+0),P(BASE+1)});
    const c32 E01 = csel(cb, c32{P(BASE+0),P(BASE+1)}, c32{P(BASE+2),P(BASE+3)});
    const c32 E10 = csel(cb, c32{P(BASE+6),P(BASE+7)}, c32{P(BASE+4),P(BASE+5)});
    const c32 E11 = csel(cb, c32{P(BASE+4),P(BASE+5)}, c32{P(BASE+6),P(BASE+7)});
    #pragma unroll
    for (int r = 0; r < 16; ++r) if (!(r & RM)) {
        c32 lo = s[r], hi = s[r|RM];
        s[r]    = cadd(cmul(E00,lo), cmul(E01,hi));
        s[r|RM] = cadd(cmul(E10,lo), cmul(E11,hi));
    }
}
template<int RM, int CRM, int BASE>
__device__ __forceinline__ void pool_regc(c32 s[16], PP pp) {
    const c32 V00{P(BASE+0),P(BASE+1)}, V01{P(BASE+2),P(BASE+3)};
    const c32 V10{P(BASE+4),P(BASE+5)}, V11{P(BASE+6),P(BASE+7)};
    #pragma unroll
    for (int r = 0; r < 16; ++r) if (!(r & RM)) {
        const bool swp = (r & CRM) != 0;
        const c32 A = swp ? V01 : V00, Bm = swp ? V00 : V01;
        const c32 C = swp ? V11 : V10, D  = swp ? V10 : V11;
        c32 lo = s[r], hi = s[r|RM];
        s[r]    = cadd(cmul(A,lo),  cmul(Bm,hi));
        s[r|RM] = cadd(cmul(C,lo),  cmul(D,hi));
    }
}

__device__ __forceinline__ float tanh_fast(float x) {
    float e = __expf(2.f * x);
    return (e - 1.f) / (e + 1.f);
}

// ---- S0: fused gate-parameter setup (verbatim) ----
__global__ void qcnn_setup(const float* __restrict__ rz,  const float* __restrict__ ry,
                           const float* __restrict__ ry2, const float* __restrict__ pool,
                           const float* __restrict__ W1,  const float* __restrict__ b1,
                           const float* __restrict__ W2,  const float* __restrict__ b2) {
    if (threadIdx.x != 0 || blockIdx.x != 0) return;
    float* ws = g_par;
    const bool hasD[10] = {true,true,true,true,false,false,false,true,true,false};
    for (int cc = 0; cc < 10; ++cc) {
        float tz = rz[cc], ta = ry[cc], tb = ry2[cc];
        float cz = cosf(0.5f*tz), szz = sinf(0.5f*tz);
        float cp = cosf(0.5f*(ta+tb)), sp = sinf(0.5f*(ta+tb));
        float cm = cosf(0.5f*(ta-tb)), sm = sinf(0.5f*(ta-tb));
        float A0[2][2] = {{cp,-sp},{sp,cp}};
        float A1[2][2] = {{sm,cm},{cm,-sm}};
        float* o = ws + 16*cc;
        for (int which = 0; which < 2; ++which) {
            float px = cz, py = which ? szz : -szz;
            for (int row = 0; row < 2; ++row)
              for (int col = 0; col < 2; ++col) {
                float ex = which ? A1[row][col] : A0[row][col], ey = 0.f;
                if (hasD[cc] && col == 1) { ey = -ex; ex = 0.f; }
                o[which*8 + row*4 + col*2 + 0] = px*ex - py*ey;
                o[which*8 + row*4 + col*2 + 1] = px*ey + py*ex;
            }
        }
    }
    const bool hasS[6] = {true,true,true,false,true,false};
    for (int pc = 0; pc < 6; ++pc) {
        float th = pool[3*pc], ph = pool[3*pc+1], la = pool[3*pc+2];
        float ct = cosf(0.5f*th), st = sinf(0.5f*th);
        float u[2][2][2] = {
            {{ct, 0.f},           {-cosf(la)*st, -sinf(la)*st}},
            {{cosf(ph)*st, sinf(ph)*st}, {cosf(ph+la)*ct, sinf(ph+la)*ct}}};
        if (hasS[pc]) {
            for (int row = 0; row < 2; ++row) {
                float xx = u[row][1][0], yy = u[row][1][1];
                u[row][1][0] = -yy; u[row][1][1] = xx;
            }
        }
        float* o = ws + 160 + 8*pc;
        for (int row = 0; row < 2; ++row) for (int col = 0; col < 2; ++col) {
            o[row*4+col*2+0] = u[row][col][0];
            o[row*4+col*2+1] = u[row][col][1];
        }
    }
    for (int i = 0; i < 20; ++i) ws[208+i] = W1[i];
    for (int i = 0; i < 10; ++i) { ws[228+i] = b1[i]; ws[238+i] = W2[i]; }
    ws[248] = b2[0];
}

// ---- S1: grid evaluation (verbatim from v7, no divergent exit) ----
__launch_bounds__(256)
__global__ void qcnn_eval_grid() {
    const int lane = threadIdx.x & 63;
    const int sub  = lane & 15;
    int i3 = lane + 192; if (i3 > 248) i3 = 248;
    PP pp{ g_par[lane], g_par[lane+64], g_par[lane+128], g_par[i3] };
    const int gwave = (blockIdx.x * blockDim.x + threadIdx.x) >> 6;
    const int b = gwave * 4 + (lane >> 4);

    const float H = 0.8660254037844386f;
    float cw[8], sw_[8];
    int rr = b;
    #pragma unroll
    for (int w = 0; w < 8; ++w) {
        int t = rr % 3; rr /= 3;
        cw[w]  = (t == 0) ? 1.f : 0.5f;
        sw_[w] = (t == 0) ? 0.f : ((t == 1) ? H : -H);
    }

    float a = ((sub & 8) ? sw_[0] : cw[0]);
    a *= (sub & 1) ? sw_[2] : cw[2];
    a *= (sub & 2) ? sw_[4] : cw[4];
    a *= (sub & 4) ? sw_[6] : cw[6];

    c32 s[16];
    float a13[4] = {cw[1]*cw[3], sw_[1]*cw[3], cw[1]*sw_[3], sw_[1]*sw_[3]};
    float a57[4] = {cw[5]*cw[7], sw_[5]*cw[7], cw[5]*sw_[7], sw_[5]*sw_[7]};
    #pragma unroll
    for (int r = 0; r < 16; ++r) s[r] = c32{ a * a13[r & 3] * a57[r >> 2], 0.f };

    conv_A<1, 8, false,  0>(s, sub, pp);
    conv_A<2, 1, true,  16>(s, sub, pp);
    conv_A<4, 2, true,  32>(s, sub, pp);
    conv_A<8, 4, true,  48>(s, sub, pp);
    conv_B<1, 1, 64>(s, sub, pp);
    conv_B<2, 2, 80>(s, sub, pp);
    conv_B<4, 4, 96>(s, sub, pp);
    pool_lanec<1, 1, 160>(s, sub, pp);
    pool_lanec<2, 2, 168>(s, sub, pp);
    pool_lanec<4, 4, 176>(s, sub, pp);
    pool_plain<8, 184>(s, pp);
    conv_RR<1, 2, false, 112>(s, pp);
    conv_RR<4, 8, true,  128>(s, pp);
    conv_RR<2, 4, false, 144>(s, pp);
    pool_regc<2, 4, 192>(s, pp);
    pool_plain<8, 200>(s, pp);

    float e3 = 0.f, e7 = 0.f;
    #pragma unroll
    for (int r = 0; r < 16; ++r) {
        float p = s[r].x*s[r].x + s[r].y*s[r].y;
        e3 += (r & 2) ? -p : p;
        e7 += (r & 8) ? -p : p;
    }
    e3 += sx<1>(e3); e3 += sx<2>(e3); e3 += sx<4>(e3); e3 += sx<8>(e3);
    e7 += sx<1>(e7); e7 += sx<2>(e7); e7 += sx<4>(e7); e7 += sx<8>(e7);

    if (sub == 0 && b < 6561) { g_E[b] = e3; g_E[6561 + b] = e7; }
}

// ---- S2: inverse-Vandermonde; emit padded [tensor][j=81][b=9][a=12] ----
__global__ void qcnn_transform() {
    __shared__ float E[13122];
    const int tid = threadIdx.x;
    const int NT = 1024;
    for (int i = tid; i < 13122; i += NT) E[i] = g_E[i];
    __syncthreads();
    int s = 1;
    for (int w = 0; w < 8; ++w) {
        for (int gg = tid; gg < 4374; gg += NT) {
            int obs = (gg >= 2187) ? 1 : 0;
            int g = gg - obs * 2187;
            int base = (g / s) * (3 * s) + (g % s) + obs * 6561;
            float a = E[base], b = E[base + s], c = E[base + 2 * s];
            E[base]         = (a + b + c) * 0.3333333333333333f;
            E[base + s]     = (2.f * a - b - c) * 0.3333333333333333f;
            E[base + 2 * s] = (b - c) * 0.5773502691896258f;
        }
        __syncthreads();
        s *= 3;
    }
    // g_T[t][j][b][a] = coeff at m = j + 81*(a + 9b);  a in [0,9) else pad 0
    for (int i = tid; i < 17496; i += NT) {
        int t = i / 8748, rem = i % 8748;
        int j = rem / 108, w = rem % 108;
        int b = w / 12, a = w % 12;
        g_T[i] = (a < 9) ? E[t * 6561 + j + 81 * (a + 9 * b)] : 0.f;
    }
}

// ---- apply inner: one jj row, b-subset [B0,B1), 4 elements ----
template<int B0, int B1>
__device__ __forceinline__ void row_dot(const float* __restrict__ Trow,
                                        const float (&p)[4][9], const float (&q)[4][9],
                                        float (&y)[4]) {
    #pragma unroll
    for (int b = B0; b < B1; ++b) {
        const float4 T0 = *reinterpret_cast<const float4*>(Trow + b*12);
        const float4 T1 = *reinterpret_cast<const float4*>(Trow + b*12 + 4);
        const float  T8 = Trow[b*12 + 8];
        #pragma unroll
        for (int e = 0; e < 4; ++e) {
            float sacc = T0.x * p[e][0];
            sacc = fmaf(T0.y, p[e][1], sacc);
            sacc = fmaf(T0.z, p[e][2], sacc);
            sacc = fmaf(T0.w, p[e][3], sacc);
            sacc = fmaf(T1.x, p[e][4], sacc);
            sacc = fmaf(T1.y, p[e][5], sacc);
            sacc = fmaf(T1.z, p[e][6], sacc);
            sacc = fmaf(T1.w, p[e][7], sacc);
            sacc = fmaf(T8,   p[e][8], sacc);
            y[e] = fmaf(q[e][b], sacc, y[e]);
        }
    }
}

// ---- M: 768 threads = 12 role-waves x 64 groups; 4 elements/thread ----
__launch_bounds__(768, 3)
__global__ void qcnn_apply(const float* __restrict__ x, float* __restrict__ out, int B) {
    __shared__ __align__(16) float Tl[17496 + 12*64*4];
    float* Pl = Tl + 17496;
    {
        float4* Td = reinterpret_cast<float4*>(Tl);
        const float4* Ts = reinterpret_cast<const float4*>(g_T);
        for (int i = threadIdx.x; i < 4374; i += 768) Td[i] = Ts[i];
    }

    const int tid  = threadIdx.x;
    const int lane = tid & 63;
    const int wave = tid >> 6;           // 0..11 = role
    const int tt   = wave & 1;           // tensor: 0 -> T3, 1 -> T7
    const int rest = wave >> 1;          // 0..5
    const int t3   = rest % 3;
    const int bh   = rest / 3;           // b-half: 0 -> b 0..3, 1 -> b 4..8

    const int gbase = (blockIdx.x * 64 + lane) * 4;

    // --- per-element basis (4 elements) ---
    float p[4][9], q[4][9], g10[4][9];
    float g3v[4], C2v[4], S2v[4];
    #pragma unroll
    for (int e = 0; e < 4; ++e) {
        int idx = gbase + e; if (idx >= B) idx = B - 1;
        const float4 xa = *reinterpret_cast<const float4*>(x + idx*8);
        const float4 xb = *reinterpret_cast<const float4*>(x + idx*8 + 4);
        float C0 = __cosf(xa.x), S0 = __sinf(xa.x);
        float C1 = __cosf(xa.y), S1 = __sinf(xa.y);
        float C2 = __cosf(xa.z), S2 = __sinf(xa.z);
        float C3 = __cosf(xa.w), S3 = __sinf(xa.w);
        float C4 = __cosf(xb.x), S4 = __sinf(xb.x);
        float C5 = __cosf(xb.y), S5 = __sinf(xb.y);
        float C6 = __cosf(xb.z), S6 = __sinf(xb.z);
        float C7 = __cosf(xb.w), S7 = __sinf(xb.w);
        g10[e][0]=1.f;  g10[e][1]=C0;    g10[e][2]=S0;
        g10[e][3]=C1;   g10[e][4]=C1*C0; g10[e][5]=C1*S0;
        g10[e][6]=S1;   g10[e][7]=S1*C0; g10[e][8]=S1*S0;
        p[e][0]=1.f;    p[e][1]=C4;      p[e][2]=S4;
        p[e][3]=C5;     p[e][4]=C5*C4;   p[e][5]=C5*S4;
        p[e][6]=S5;     p[e][7]=S5*C4;   p[e][8]=S5*S4;
        q[e][0]=1.f;    q[e][1]=C6;      q[e][2]=S6;
        q[e][3]=C7;     q[e][4]=C7*C6;   q[e][5]=C7*S6;
        q[e][6]=S7;     q[e][7]=S7*C6;   q[e][8]=S7*S6;
        g3v[e] = (t3 == 0) ? 1.f : ((t3 == 1) ? C3 : S3);
        C2v[e] = C2; S2v[e] = S2;
    }

    __syncthreads();

    // --- contraction over this role's slice ---
    float acc[4] = {0.f, 0.f, 0.f, 0.f};
    const float* Tt = Tl + tt * 8748 + t3 * 27 * 108;
    for (int t2 = 0; t2 < 3; ++t2) {
        float u23[4];
        #pragma unroll
        for (int e = 0; e < 4; ++e) {
            float g2 = (t2 == 0) ? 1.f : ((t2 == 1) ? C2v[e] : S2v[e]);
            u23[e] = g3v[e] * g2;
        }
        const float* rb = Tt + t2 * 9 * 108;
        #pragma unroll
        for (int jj = 0; jj < 9; ++jj) {
            float y[4] = {0.f, 0.f, 0.f, 0.f};
            if (bh == 0) row_dot<0, 4>(rb + jj*108, p, q, y);
            else         row_dot<4, 9>(rb + jj*108, p, q, y);
            #pragma unroll
            for (int e = 0; e < 4; ++e)
                acc[e] = fmaf(u23[e] * g10[e][jj], y[e], acc[e]);
        }
    }

    // --- combine partials across the 12 role-waves ---
    #pragma unroll
    for (int e = 0; e < 4; ++e) Pl[wave*256 + lane*4 + e] = acc[e];
    __syncthreads();

    if (tid < 256) {
        const int elem = blockIdx.x * 256 + tid;
        if (elem < B) {
            const int off = (tid >> 2) * 4 + (tid & 3);   // = tid
            float e3 = 0.f, e7 = 0.f;
            #pragma unroll
            for (int r = 0; r < 6; ++r) {
                e3 += Pl[(2*r)   * 256 + off];
                e7 += Pl[(2*r+1) * 256 + off];
            }
            float z = g_par[248];
            #pragma unroll
            for (int i = 0; i < 10; ++i) {
                float h = tanh_fast(g_par[208+2*i]*e3 + g_par[209+2*i]*e7 + g_par[228+i]);
                z += g_par[238+i]*h;
            }
            out[elem] = 1.f / (1.f + __expf(-z));
        }
    }
}

extern "C" void kernel_launch(void* const* d_in, const int* in_sizes, int n_in,
                              void* d_out, int out_size, void* d_ws, size_t ws_size,
                              hipStream_t stream) {
    const float* x       = (const float*)d_in[0];
    const float* conv_rz = (const float*)d_in[1];
    const float* conv_ry = (const float*)d_in[2];
    const float* conv_ry2= (const float*)d_in[3];
    const float* pool    = (const float*)d_in[4];
    const float* W1      = (const float*)d_in[5];
    const float* b1      = (const float*)d_in[6];
    const float* W2      = (const float*)d_in[7];
    const float* b2      = (const float*)d_in[8];
    float* out = (float*)d_out;
    (void)d_ws; (void)ws_size;

    int B = in_sizes[0] / 8;

    qcnn_setup<<<1, 1, 0, stream>>>(conv_rz, conv_ry, conv_ry2, pool, W1, b1, W2, b2);
    qcnn_eval_grid<<<411, 256, 0, stream>>>();
    qcnn_transform<<<1, 1024, 0, stream>>>();
    qcnn_apply<<<(B + 255) / 256, 768, 0, stream>>>(x, out, B);
}

// Round 9
// 56.704 us; speedup vs baseline: 2.6447x; 1.2372x over previous
//
#include <hip/hip_runtime.h>
#include <math.h>

// ---------------------------------------------------------------------------
// QCNN 8-qubit statevector, v9: 2-kernel pipeline.
//   K1 qcnn_eval_grid: in-block fused-param setup (parallel trig) + evaluate
//      e3/e7 on the 3^8 grid {0, +-2pi/3}, writing DIRECTLY into the padded
//      tensor layout g_T[t][j=81][bq=9][a pad 12].
//   K2 qcnn_apply: Lagrange cardinal contraction — e = sum_b E_b Prod_w
//      L_{t_w}(x_w) with L0=(1+2c)/3, L1/L2=(1-c)/3 +- s/sqrt(3). This makes
//      the inverse-Vandermonde transform kernel unnecessary (exact identity).
//      12 role-waves x 4 elems/thread, T broadcast from LDS; MLP tail reads
//      W1/b1/W2/b2 directly from global.
// ---------------------------------------------------------------------------

__device__ __align__(16) float g_T[17496];

struct c32 { float x, y; };
__device__ __forceinline__ c32 cmul(c32 a, c32 b){ return c32{a.x*b.x - a.y*b.y, a.x*b.y + a.y*b.x}; }
__device__ __forceinline__ c32 cadd(c32 a, c32 b){ return c32{a.x+b.x, a.y+b.y}; }
__device__ __forceinline__ c32 csel(bool c, c32 a, c32 b){ return c32{c?a.x:b.x, c?a.y:b.y}; }

struct PP { float a, b, c, d; };

__device__ __forceinline__ float pget(int i, PP pp) {
    float s = (i < 64) ? pp.a : (i < 128) ? pp.b : (i < 192) ? pp.c : pp.d;
    return __uint_as_float(__builtin_amdgcn_readlane(__float_as_uint(s), i & 63));
}
#define P(I) pget((I), pp)

template<int M>
__device__ __forceinline__ float sx(float v) {
    if constexpr (M == 1) {
        return __int_as_float(__builtin_amdgcn_update_dpp(
            __float_as_int(v), __float_as_int(v), 0xB1, 0xF, 0xF, false));
    } else if constexpr (M == 2) {
        return __int_as_float(__builtin_amdgcn_update_dpp(
            __float_as_int(v), __float_as_int(v), 0x4E, 0xF, 0xF, false));
    } else if constexpr (M == 4) {
        return __int_as_float(__builtin_amdgcn_ds_swizzle(__float_as_int(v), 0x101F));
    } else {
        return __int_as_float(__builtin_amdgcn_ds_swizzle(__float_as_int(v), 0x201F));
    }
}

// ---- fused-conv machinery (verbatim, verified v4..v8) ----
template<int RM, int LQ, bool KEEPD, int BASE>
__device__ __forceinline__ void conv_A(c32 s[16], int sub, PP pp) {
    #pragma unroll
    for (int r = 0; r < 16; ++r) if (r & RM) { s[r].x = sx<LQ>(s[r].x); s[r].y = sx<LQ>(s[r].y); }
    const bool cb = (sub & LQ) != 0;
    const c32 M00 = csel(cb, c32{P(BASE+8),P(BASE+9)},   c32{P(BASE+0),P(BASE+1)});
    const c32 M01 = csel(cb, c32{P(BASE+10),P(BASE+11)}, c32{P(BASE+2),P(BASE+3)});
    const c32 M10 = csel(cb, c32{P(BASE+12),P(BASE+13)}, c32{P(BASE+4),P(BASE+5)});
    const c32 M11 = csel(cb, c32{P(BASE+14),P(BASE+15)}, c32{P(BASE+6),P(BASE+7)});
    #pragma unroll
    for (int r = 0; r < 16; ++r) if (!(r & RM)) {
        c32 lo = s[r], hi = s[r|RM];
        s[r]    = cadd(cmul(M00,lo), cmul(M01,hi));
        s[r|RM] = cadd(cmul(M10,lo), cmul(M11,hi));
    }
    if constexpr (KEEPD) {
        #pragma unroll
        for (int r = 0; r < 16; ++r) if (r & RM) { s[r].x = sx<LQ>(s[r].x); s[r].y = sx<LQ>(s[r].y); }
    }
}

template<int RM, int LQ, int BASE>
__device__ __forceinline__ void conv_B(c32 s[16], int sub, PP pp) {
    const bool cb = (sub & LQ) != 0;
    #pragma unroll
    for (int r = 0; r < 16; ++r) if (!(r & RM)) {
        c32 lo = s[r], hi = s[r|RM];
        s[r]    = csel(cb, hi, lo);
        s[r|RM] = csel(cb, lo, hi);
    }
    const c32 RS0 = csel(cb, c32{P(BASE+6),P(BASE+7)},   c32{P(BASE+0),P(BASE+1)});
    const c32 RP0 = csel(cb, c32{P(BASE+4),P(BASE+5)},   c32{P(BASE+2),P(BASE+3)});
    const c32 RS1 = csel(cb, c32{P(BASE+14),P(BASE+15)}, c32{P(BASE+8),P(BASE+9)});
    const c32 RP1 = csel(cb, c32{P(BASE+12),P(BASE+13)}, c32{P(BASE+10),P(BASE+11)});
    #pragma unroll
    for (int r = 0; r < 16; ++r) {
        c32 pt{ sx<LQ>(s[r].x), sx<LQ>(s[r].y) };
        const c32 RS = (r & RM) ? RS1 : RS0;
        const c32 RP = (r & RM) ? RP1 : RP0;
        s[r] = cadd(cmul(RS, s[r]), cmul(RP, pt));
    }
}

template<int CM, int TM, bool KEEPD, int BASE>
__device__ __forceinline__ void conv_RR(c32 s[16], PP pp) {
    c32 m[2][2][2];
    #pragma unroll
    for (int q = 0; q < 2; ++q)
      #pragma unroll
      for (int i = 0; i < 2; ++i)
        #pragma unroll
        for (int j = 0; j < 2; ++j)
          m[q][i][j] = c32{ P(BASE + q*8 + i*4 + j*2), P(BASE + q*8 + i*4 + j*2 + 1) };
    #pragma unroll
    for (int r = 0; r < 16; ++r) if ((r & TM) && !(r & CM)) { c32 t = s[r]; s[r] = s[r|CM]; s[r|CM] = t; }
    #pragma unroll
    for (int r = 0; r < 16; ++r) if (!(r & TM)) {
        const int q = (r & CM) ? 1 : 0;
        c32 lo = s[r], hi = s[r|TM];
        s[r]    = cadd(cmul(m[q][0][0],lo), cmul(m[q][0][1],hi));
        s[r|TM] = cadd(cmul(m[q][1][0],lo), cmul(m[q][1][1],hi));
    }
    if constexpr (KEEPD) {
        #pragma unroll
        for (int r = 0; r < 16; ++r) if ((r & TM) && !(r & CM)) { c32 t = s[r]; s[r] = s[r|CM]; s[r|CM] = t; }
    }
}

template<int RM, int BASE>
__device__ __forceinline__ void pool_plain(c32 s[16], PP pp) {
    const c32 V00{P(BASE+0),P(BASE+1)}, V01{P(BASE+2),P(BASE+3)};
    const c32 V10{P(BASE+4),P(BASE+5)}, V11{P(BASE+6),P(BASE+7)};
    #pragma unroll
    for (int r = 0; r < 16; ++r) if (!(r & RM)) {
        c32 lo = s[r], hi = s[r|RM];
        s[r]    = cadd(cmul(V00,lo), cmul(V01,hi));
        s[r|RM] = cadd(cmul(V10,lo), cmul(V11,hi));
    }
}
template<int RM, int LQ, int BASE>
__device__ __forceinline__ void pool_lanec(c32 s[16], int sub, PP pp) {
    const bool cb = (sub & LQ) != 0;
    const c32 E00 = csel(cb, c32{P(BASE+2),P(BASE+3)}, c32{P(BASE+0),P(BASE+1)});
    const c32 E01 = csel(cb, c32{P(BASE+0),P(BASE+1)}, c32{P(BASE+2),P(BASE+3)});
    const c32 E10 = csel(cb, c32{P(BASE+6),P(BASE+7)}, c32{P(BASE+4),P(BASE+5)});
    const c32 E11 = csel(cb, c32{P(BASE+4),P(BASE+5)}, c32{P(BASE+6),P(BASE+7)});
    #pragma unroll
    for (int r = 0; r < 16; ++r) if (!(r & RM)) {
        c32 lo = s[r], hi = s[r|RM];
        s[r]    = cadd(cmul(E00,lo), cmul(E01,hi));
        s[r|RM] = cadd(cmul(E10,lo), cmul(E11,hi));
    }
}
template<int RM, int CRM, int BASE>
__device__ __forceinline__ void pool_regc(c32 s[16], PP pp) {
    const c32 V00{P(BASE+0),P(BASE+1)}, V01{P(BASE+2),P(BASE+3)};
    const c32 V10{P(BASE+4),P(BASE+5)}, V11{P(BASE+6),P(BASE+7)};
    #pragma unroll
    for (int r = 0; r < 16; ++r) if (!(r & RM)) {
        const bool swp = (r & CRM) != 0;
        const c32 A = swp ? V01 : V00, Bm = swp ? V00 : V01;
        const c32 C = swp ? V11 : V10, D  = swp ? V10 : V11;
        c32 lo = s[r], hi = s[r|RM];
        s[r]    = cadd(cmul(A,lo),  cmul(Bm,hi));
        s[r|RM] = cadd(cmul(C,lo),  cmul(D,hi));
    }
}

__device__ __forceinline__ float tanh_fast(float x) {
    float e = __expf(2.f * x);
    return (e - 1.f) / (e + 1.f);
}

// ---- K1: in-block param setup + grid eval, writes g_T padded layout ----
__launch_bounds__(256)
__global__ void qcnn_eval_grid(const float* __restrict__ rz,  const float* __restrict__ ry,
                               const float* __restrict__ ry2, const float* __restrict__ pool) {
    __shared__ float par[256];
    const int tid = threadIdx.x;

    if (tid < 10) {
        // fused conv matrices (same math as v4 setup), cc = tid
        const int cc = tid;
        const bool hasD = (cc <= 3) || (cc == 7) || (cc == 8);
        float tz = rz[cc], ta = ry[cc], tb = ry2[cc];
        float cz = __cosf(0.5f*tz), szz = __sinf(0.5f*tz);
        float cp = __cosf(0.5f*(ta+tb)), sp = __sinf(0.5f*(ta+tb));
        float cm = __cosf(0.5f*(ta-tb)), sm = __sinf(0.5f*(ta-tb));
        float A0[2][2] = {{cp,-sp},{sp,cp}};
        float A1[2][2] = {{sm,cm},{cm,-sm}};
        float* o = par + 16*cc;
        #pragma unroll
        for (int which = 0; which < 2; ++which) {
            float px = cz, py = which ? szz : -szz;
            #pragma unroll
            for (int row = 0; row < 2; ++row)
              #pragma unroll
              for (int col = 0; col < 2; ++col) {
                float ex = which ? A1[row][col] : A0[row][col], ey = 0.f;
                if (hasD && col == 1) { ey = -ex; ex = 0.f; }
                o[which*8 + row*4 + col*2 + 0] = px*ex - py*ey;
                o[which*8 + row*4 + col*2 + 1] = px*ey + py*ex;
            }
        }
    } else if (tid < 16) {
        const int pc = tid - 10;
        const bool hasS = (pc <= 2) || (pc == 4);
        float th = pool[3*pc], ph = pool[3*pc+1], la = pool[3*pc+2];
        float ct = __cosf(0.5f*th), st = __sinf(0.5f*th);
        float u[2][2][2] = {
            {{ct, 0.f},                    {-__cosf(la)*st, -__sinf(la)*st}},
            {{__cosf(ph)*st, __sinf(ph)*st}, {__cosf(ph+la)*ct, __sinf(ph+la)*ct}}};
        if (hasS) {
            #pragma unroll
            for (int row = 0; row < 2; ++row) {
                float xx = u[row][1][0], yy = u[row][1][1];
                u[row][1][0] = -yy; u[row][1][1] = xx;
            }
        }
        float* o = par + 160 + 8*pc;
        #pragma unroll
        for (int row = 0; row < 2; ++row)
          #pragma unroll
          for (int col = 0; col < 2; ++col) {
            o[row*4+col*2+0] = u[row][col][0];
            o[row*4+col*2+1] = u[row][col][1];
        }
    } else if (tid < 64) {
        par[208 + (tid - 16)] = 0.f;   // 208..255 defined
    }
    __syncthreads();

    const int lane = tid & 63;
    const int sub  = lane & 15;
    PP pp{ par[lane], par[lane+64], par[lane+128], par[lane+192] };
    const int gwave = (blockIdx.x * blockDim.x + tid) >> 6;
    const int b = gwave * 4 + (lane >> 4);   // all lanes run (no divergent exit)

    const float H = 0.8660254037844386f;
    float cw[8], sw_[8];
    int rr = b;
    #pragma unroll
    for (int w = 0; w < 8; ++w) {
        int t = rr % 3; rr /= 3;
        cw[w]  = (t == 0) ? 1.f : 0.5f;
        sw_[w] = (t == 0) ? 0.f : ((t == 1) ? H : -H);
    }

    float a = ((sub & 8) ? sw_[0] : cw[0]);
    a *= (sub & 1) ? sw_[2] : cw[2];
    a *= (sub & 2) ? sw_[4] : cw[4];
    a *= (sub & 4) ? sw_[6] : cw[6];

    c32 s[16];
    float a13[4] = {cw[1]*cw[3], sw_[1]*cw[3], cw[1]*sw_[3], sw_[1]*sw_[3]};
    float a57[4] = {cw[5]*cw[7], sw_[5]*cw[7], cw[5]*sw_[7], sw_[5]*sw_[7]};
    #pragma unroll
    for (int r = 0; r < 16; ++r) s[r] = c32{ a * a13[r & 3] * a57[r >> 2], 0.f };

    conv_A<1, 8, false,  0>(s, sub, pp);
    conv_A<2, 1, true,  16>(s, sub, pp);
    conv_A<4, 2, true,  32>(s, sub, pp);
    conv_A<8, 4, true,  48>(s, sub, pp);
    conv_B<1, 1, 64>(s, sub, pp);
    conv_B<2, 2, 80>(s, sub, pp);
    conv_B<4, 4, 96>(s, sub, pp);
    pool_lanec<1, 1, 160>(s, sub, pp);
    pool_lanec<2, 2, 168>(s, sub, pp);
    pool_lanec<4, 4, 176>(s, sub, pp);
    pool_plain<8, 184>(s, pp);
    conv_RR<1, 2, false, 112>(s, pp);
    conv_RR<4, 8, true,  128>(s, pp);
    conv_RR<2, 4, false, 144>(s, pp);
    pool_regc<2, 4, 192>(s, pp);
    pool_plain<8, 200>(s, pp);

    float e3 = 0.f, e7 = 0.f;
    #pragma unroll
    for (int r = 0; r < 16; ++r) {
        float p = s[r].x*s[r].x + s[r].y*s[r].y;
        e3 += (r & 2) ? -p : p;
        e7 += (r & 8) ? -p : p;
    }
    e3 += sx<1>(e3); e3 += sx<2>(e3); e3 += sx<4>(e3); e3 += sx<8>(e3);
    e7 += sx<1>(e7); e7 += sx<2>(e7); e7 += sx<4>(e7); e7 += sx<8>(e7);

    if (sub == 0 && b < 6561) {
        // padded layout: [t][j=81][bq=9][a pad 12];  j=t0..t3, a=t4+3t5, bq=t6+3t7
        int j = b % 81, k = b / 81;
        int aa = k % 9, bq = k / 9;
        int base = j * 108 + bq * 12 + aa;
        g_T[base]        = e3;
        g_T[8748 + base] = e7;
    }
}

// ---- apply inner: one jj row, b-subset [B0,B1), 4 elements ----
template<int B0, int B1>
__device__ __forceinline__ void row_dot(const float* __restrict__ Trow,
                                        const float (&p)[4][9], const float (&q)[4][9],
                                        float (&y)[4]) {
    #pragma unroll
    for (int b = B0; b < B1; ++b) {
        const float4 T0 = *reinterpret_cast<const float4*>(Trow + b*12);
        const float4 T1 = *reinterpret_cast<const float4*>(Trow + b*12 + 4);
        const float  T8 = Trow[b*12 + 8];
        #pragma unroll
        for (int e = 0; e < 4; ++e) {
            float sacc = T0.x * p[e][0];
            sacc = fmaf(T0.y, p[e][1], sacc);
            sacc = fmaf(T0.z, p[e][2], sacc);
            sacc = fmaf(T0.w, p[e][3], sacc);
            sacc = fmaf(T1.x, p[e][4], sacc);
            sacc = fmaf(T1.y, p[e][5], sacc);
            sacc = fmaf(T1.z, p[e][6], sacc);
            sacc = fmaf(T1.w, p[e][7], sacc);
            sacc = fmaf(T8,   p[e][8], sacc);
            y[e] = fmaf(q[e][b], sacc, y[e]);
        }
    }
}

// Lagrange cardinal triple at nodes {0, 2pi/3, -2pi/3} for basis {1,cos,sin}
__device__ __forceinline__ void lag3(float xv, float& l0, float& l1, float& l2) {
    const float  A = 0.33333333333333333f;
    const float  K = 0.57735026918962576f;
    float c = __cosf(xv), s = __sinf(xv);
    l0 = fmaf(2.f * A, c, A);
    float m = A * (1.f - c);
    l1 = fmaf(K, s, m);
    l2 = fmaf(-K, s, m);
}

// ---- K2: 768 threads = 12 role-waves; 4 elements/thread; Lagrange basis ----
__launch_bounds__(768, 3)
__global__ void qcnn_apply(const float* __restrict__ x,
                           const float* __restrict__ W1, const float* __restrict__ b1,
                           const float* __restrict__ W2, const float* __restrict__ b2,
                           float* __restrict__ out, int B) {
    __shared__ __align__(16) float Tl[17496 + 12*64*4];
    float* Pl = Tl + 17496;
    {
        float4* Td = reinterpret_cast<float4*>(Tl);
        const float4* Ts = reinterpret_cast<const float4*>(g_T);
        for (int i = threadIdx.x; i < 4374; i += 768) Td[i] = Ts[i];
    }

    const int tid  = threadIdx.x;
    const int lane = tid & 63;
    const int wave = tid >> 6;           // 0..11 = role
    const int tt   = wave & 1;           // tensor: 0 -> T3, 1 -> T7
    const int rest = wave >> 1;          // 0..5
    const int t3   = rest % 3;
    const int bh   = rest / 3;           // b-half: 0 -> bq 0..3, 1 -> bq 4..8

    const int gbase = (blockIdx.x * 64 + lane) * 4;

    // --- per-element Lagrange basis (4 elements) ---
    float p[4][9], q[4][9], g10[4][9];
    float g3v[4], L20[4], L21[4], L22[4];
    #pragma unroll
    for (int e = 0; e < 4; ++e) {
        int idx = gbase + e; if (idx >= B) idx = B - 1;
        const float4 xa = *reinterpret_cast<const float4*>(x + idx*8);
        const float4 xb = *reinterpret_cast<const float4*>(x + idx*8 + 4);
        float l0[3], l1[3], l2[3], l3[3], l4[3], l5[3], l6[3], l7[3];
        lag3(xa.x, l0[0], l0[1], l0[2]);
        lag3(xa.y, l1[0], l1[1], l1[2]);
        lag3(xa.z, l2[0], l2[1], l2[2]);
        lag3(xa.w, l3[0], l3[1], l3[2]);
        lag3(xb.x, l4[0], l4[1], l4[2]);
        lag3(xb.y, l5[0], l5[1], l5[2]);
        lag3(xb.z, l6[0], l6[1], l6[2]);
        lag3(xb.w, l7[0], l7[1], l7[2]);
        #pragma unroll
        for (int u = 0; u < 3; ++u)
          #pragma unroll
          for (int v = 0; v < 3; ++v) {
            g10[e][u + 3*v] = l0[u] * l1[v];   // jj = t0 + 3 t1
            p[e][u + 3*v]   = l4[u] * l5[v];   // a  = t4 + 3 t5
            q[e][u + 3*v]   = l6[u] * l7[v];   // bq = t6 + 3 t7
        }
        g3v[e] = (t3 == 0) ? l3[0] : ((t3 == 1) ? l3[1] : l3[2]);
        L20[e] = l2[0]; L21[e] = l2[1]; L22[e] = l2[2];
    }

    __syncthreads();

    // --- contraction over this role's slice ---
    float acc[4] = {0.f, 0.f, 0.f, 0.f};
    const float* Tt = Tl + tt * 8748 + t3 * 27 * 108;
    for (int t2 = 0; t2 < 3; ++t2) {
        float u23[4];
        #pragma unroll
        for (int e = 0; e < 4; ++e) {
            float g2 = (t2 == 0) ? L20[e] : ((t2 == 1) ? L21[e] : L22[e]);
            u23[e] = g3v[e] * g2;
        }
        const float* rb = Tt + t2 * 9 * 108;
        #pragma unroll
        for (int jj = 0; jj < 9; ++jj) {
            float y[4] = {0.f, 0.f, 0.f, 0.f};
            if (bh == 0) row_dot<0, 4>(rb + jj*108, p, q, y);
            else         row_dot<4, 9>(rb + jj*108, p, q, y);
            #pragma unroll
            for (int e = 0; e < 4; ++e)
                acc[e] = fmaf(u23[e] * g10[e][jj], y[e], acc[e]);
        }
    }

    // --- combine partials across the 12 role-waves ---
    #pragma unroll
    for (int e = 0; e < 4; ++e) Pl[wave*256 + lane*4 + e] = acc[e];
    __syncthreads();

    if (tid < 256) {
        const int elem = blockIdx.x * 256 + tid;
        if (elem < B) {
            float e3 = 0.f, e7 = 0.f;
            #pragma unroll
            for (int r = 0; r < 6; ++r) {
                e3 += Pl[(2*r)   * 256 + tid];
                e7 += Pl[(2*r+1) * 256 + tid];
            }
            float z = b2[0];
            #pragma unroll
            for (int i = 0; i < 10; ++i) {
                float h = tanh_fast(W1[2*i]*e3 + W1[2*i+1]*e7 + b1[i]);
                z += W2[i]*h;
            }
            out[elem] = 1.f / (1.f + __expf(-z));
        }
    }
}

extern "C" void kernel_launch(void* const* d_in, const int* in_sizes, int n_in,
                              void* d_out, int out_size, void* d_ws, size_t ws_size,
                              hipStream_t stream) {
    const float* x       = (const float*)d_in[0];
    const float* conv_rz = (const float*)d_in[1];
    const float* conv_ry = (const float*)d_in[2];
    const float* conv_ry2= (const float*)d_in[3];
    const float* pool    = (const float*)d_in[4];
    const float* W1      = (const float*)d_in[5];
    const float* b1      = (const float*)d_in[6];
    const float* W2      = (const float*)d_in[7];
    const float* b2      = (const float*)d_in[8];
    float* out = (float*)d_out;
    (void)d_ws; (void)ws_size;

    int B = in_sizes[0] / 8;

    qcnn_eval_grid<<<411, 256, 0, stream>>>(conv_rz, conv_ry, conv_ry2, pool);
    qcnn_apply<<<(B + 255) / 256, 768, 0, stream>>>(x, W1, b1, W2, b2, out, B);
}

// Round 10
// 46.640 us; speedup vs baseline: 3.2153x; 1.2158x over previous
//
#include <hip/hip_runtime.h>
#include <math.h>

// ---------------------------------------------------------------------------
// QCNN 8-qubit statevector, v10: 2-kernel pipeline, T read from GLOBAL.
//   K1 qcnn_eval_grid: in-block param setup + 3^8 grid eval, writes
//      Tmain[t][j=81][bq=9][a=8] (+ T8 plane [t][j=81][12]) in g_T.
//   K2 qcnn_apply: Lagrange cardinal contraction. T rows are wave-uniform ->
//      read DIRECTLY from global via readfirstlane-scalarized offsets
//      (s_load/uniform-VMEM path, L2-hot) — LDS pipe freed (v9 was
//      LDS-broadcast-bound at 16 B/instr). LDS holds only the 12 KB
//      partial-combine buffer. 12 role-waves, E=4, bq-balanced 13/14 rows.
// g_T layout (floats): [0..5831] Tmain t=0 | [5832..11663] Tmain t=1 |
//                      [11664..12635] T8 t=0 | [12636..13607] T8 t=1
// ---------------------------------------------------------------------------

__device__ __align__(16) float g_T[13608];

struct c32 { float x, y; };
__device__ __forceinline__ c32 cmul(c32 a, c32 b){ return c32{a.x*b.x - a.y*b.y, a.x*b.y + a.y*b.x}; }
__device__ __forceinline__ c32 cadd(c32 a, c32 b){ return c32{a.x+b.x, a.y+b.y}; }
__device__ __forceinline__ c32 csel(bool c, c32 a, c32 b){ return c32{c?a.x:b.x, c?a.y:b.y}; }

struct PP { float a, b, c, d; };

__device__ __forceinline__ float pget(int i, PP pp) {
    float s = (i < 64) ? pp.a : (i < 128) ? pp.b : (i < 192) ? pp.c : pp.d;
    return __uint_as_float(__builtin_amdgcn_readlane(__float_as_uint(s), i & 63));
}
#define P(I) pget((I), pp)

template<int M>
__device__ __forceinline__ float sx(float v) {
    if constexpr (M == 1) {
        return __int_as_float(__builtin_amdgcn_update_dpp(
            __float_as_int(v), __float_as_int(v), 0xB1, 0xF, 0xF, false));
    } else if constexpr (M == 2) {
        return __int_as_float(__builtin_amdgcn_update_dpp(
            __float_as_int(v), __float_as_int(v), 0x4E, 0xF, 0xF, false));
    } else if constexpr (M == 4) {
        return __int_as_float(__builtin_amdgcn_ds_swizzle(__float_as_int(v), 0x101F));
    } else {
        return __int_as_float(__builtin_amdgcn_ds_swizzle(__float_as_int(v), 0x201F));
    }
}

// ---- fused-conv machinery (verbatim, verified v4..v9) ----
template<int RM, int LQ, bool KEEPD, int BASE>
__device__ __forceinline__ void conv_A(c32 s[16], int sub, PP pp) {
    #pragma unroll
    for (int r = 0; r < 16; ++r) if (r & RM) { s[r].x = sx<LQ>(s[r].x); s[r].y = sx<LQ>(s[r].y); }
    const bool cb = (sub & LQ) != 0;
    const c32 M00 = csel(cb, c32{P(BASE+8),P(BASE+9)},   c32{P(BASE+0),P(BASE+1)});
    const c32 M01 = csel(cb, c32{P(BASE+10),P(BASE+11)}, c32{P(BASE+2),P(BASE+3)});
    const c32 M10 = csel(cb, c32{P(BASE+12),P(BASE+13)}, c32{P(BASE+4),P(BASE+5)});
    const c32 M11 = csel(cb, c32{P(BASE+14),P(BASE+15)}, c32{P(BASE+6),P(BASE+7)});
    #pragma unroll
    for (int r = 0; r < 16; ++r) if (!(r & RM)) {
        c32 lo = s[r], hi = s[r|RM];
        s[r]    = cadd(cmul(M00,lo), cmul(M01,hi));
        s[r|RM] = cadd(cmul(M10,lo), cmul(M11,hi));
    }
    if constexpr (KEEPD) {
        #pragma unroll
        for (int r = 0; r < 16; ++r) if (r & RM) { s[r].x = sx<LQ>(s[r].x); s[r].y = sx<LQ>(s[r].y); }
    }
}

template<int RM, int LQ, int BASE>
__device__ __forceinline__ void conv_B(c32 s[16], int sub, PP pp) {
    const bool cb = (sub & LQ) != 0;
    #pragma unroll
    for (int r = 0; r < 16; ++r) if (!(r & RM)) {
        c32 lo = s[r], hi = s[r|RM];
        s[r]    = csel(cb, hi, lo);
        s[r|RM] = csel(cb, lo, hi);
    }
    const c32 RS0 = csel(cb, c32{P(BASE+6),P(BASE+7)},   c32{P(BASE+0),P(BASE+1)});
    const c32 RP0 = csel(cb, c32{P(BASE+4),P(BASE+5)},   c32{P(BASE+2),P(BASE+3)});
    const c32 RS1 = csel(cb, c32{P(BASE+14),P(BASE+15)}, c32{P(BASE+8),P(BASE+9)});
    const c32 RP1 = csel(cb, c32{P(BASE+12),P(BASE+13)}, c32{P(BASE+10),P(BASE+11)});
    #pragma unroll
    for (int r = 0; r < 16; ++r) {
        c32 pt{ sx<LQ>(s[r].x), sx<LQ>(s[r].y) };
        const c32 RS = (r & RM) ? RS1 : RS0;
        const c32 RP = (r & RM) ? RP1 : RP0;
        s[r] = cadd(cmul(RS, s[r]), cmul(RP, pt));
    }
}

template<int CM, int TM, bool KEEPD, int BASE>
__device__ __forceinline__ void conv_RR(c32 s[16], PP pp) {
    c32 m[2][2][2];
    #pragma unroll
    for (int q = 0; q < 2; ++q)
      #pragma unroll
      for (int i = 0; i < 2; ++i)
        #pragma unroll
        for (int j = 0; j < 2; ++j)
          m[q][i][j] = c32{ P(BASE + q*8 + i*4 + j*2), P(BASE + q*8 + i*4 + j*2 + 1) };
    #pragma unroll
    for (int r = 0; r < 16; ++r) if ((r & TM) && !(r & CM)) { c32 t = s[r]; s[r] = s[r|CM]; s[r|CM] = t; }
    #pragma unroll
    for (int r = 0; r < 16; ++r) if (!(r & TM)) {
        const int q = (r & CM) ? 1 : 0;
        c32 lo = s[r], hi = s[r|TM];
        s[r]    = cadd(cmul(m[q][0][0],lo), cmul(m[q][0][1],hi));
        s[r|TM] = cadd(cmul(m[q][1][0],lo), cmul(m[q][1][1],hi));
    }
    if constexpr (KEEPD) {
        #pragma unroll
        for (int r = 0; r < 16; ++r) if ((r & TM) && !(r & CM)) { c32 t = s[r]; s[r] = s[r|CM]; s[r|CM] = t; }
    }
}

template<int RM, int BASE>
__device__ __forceinline__ void pool_plain(c32 s[16], PP pp) {
    const c32 V00{P(BASE+0),P(BASE+1)}, V01{P(BASE+2),P(BASE+3)};
    const c32 V10{P(BASE+4),P(BASE+5)}, V11{P(BASE+6),P(BASE+7)};
    #pragma unroll
    for (int r = 0; r < 16; ++r) if (!(r & RM)) {
        c32 lo = s[r], hi = s[r|RM];
        s[r]    = cadd(cmul(V00,lo), cmul(V01,hi));
        s[r|RM] = cadd(cmul(V10,lo), cmul(V11,hi));
    }
}
template<int RM, int LQ, int BASE>
__device__ __forceinline__ void pool_lanec(c32 s[16], int sub, PP pp) {
    const bool cb = (sub & LQ) != 0;
    const c32 E00 = csel(cb, c32{P(BASE+2),P(BASE+3)}, c32{P(BASE+0),P(BASE+1)});
    const c32 E01 = csel(cb, c32{P(BASE+0),P(BASE+1)}, c32{P(BASE+2),P(BASE+3)});
    const c32 E10 = csel(cb, c32{P(BASE+6),P(BASE+7)}, c32{P(BASE+4),P(BASE+5)});
    const c32 E11 = csel(cb, c32{P(BASE+4),P(BASE+5)}, c32{P(BASE+6),P(BASE+7)});
    #pragma unroll
    for (int r = 0; r < 16; ++r) if (!(r & RM)) {
        c32 lo = s[r], hi = s[r|RM];
        s[r]    = cadd(cmul(E00,lo), cmul(E01,hi));
        s[r|RM] = cadd(cmul(E10,lo), cmul(E11,hi));
    }
}
template<int RM, int CRM, int BASE>
__device__ __forceinline__ void pool_regc(c32 s[16], PP pp) {
    const c32 V00{P(BASE+0),P(BASE+1)}, V01{P(BASE+2),P(BASE+3)};
    const c32 V10{P(BASE+4),P(BASE+5)}, V11{P(BASE+6),P(BASE+7)};
    #pragma unroll
    for (int r = 0; r < 16; ++r) if (!(r & RM)) {
        const bool swp = (r & CRM) != 0;
        const c32 A = swp ? V01 : V00, Bm = swp ? V00 : V01;
        const c32 C = swp ? V11 : V10, D  = swp ? V10 : V11;
        c32 lo = s[r], hi = s[r|RM];
        s[r]    = cadd(cmul(A,lo),  cmul(Bm,hi));
        s[r|RM] = cadd(cmul(C,lo),  cmul(D,hi));
    }
}

__device__ __forceinline__ float tanh_fast(float x) {
    float e = __expf(2.f * x);
    return (e - 1.f) / (e + 1.f);
}

// ---- K1: in-block param setup + grid eval, writes g_T (Tmain + T8) ----
__launch_bounds__(256)
__global__ void qcnn_eval_grid(const float* __restrict__ rz,  const float* __restrict__ ry,
                               const float* __restrict__ ry2, const float* __restrict__ pool) {
    __shared__ float par[256];
    const int tid = threadIdx.x;

    if (tid < 10) {
        const int cc = tid;
        const bool hasD = (cc <= 3) || (cc == 7) || (cc == 8);
        float tz = rz[cc], ta = ry[cc], tb = ry2[cc];
        float cz = __cosf(0.5f*tz), szz = __sinf(0.5f*tz);
        float cp = __cosf(0.5f*(ta+tb)), sp = __sinf(0.5f*(ta+tb));
        float cm = __cosf(0.5f*(ta-tb)), sm = __sinf(0.5f*(ta-tb));
        float A0[2][2] = {{cp,-sp},{sp,cp}};
        float A1[2][2] = {{sm,cm},{cm,-sm}};
        float* o = par + 16*cc;
        #pragma unroll
        for (int which = 0; which < 2; ++which) {
            float px = cz, py = which ? szz : -szz;
            #pragma unroll
            for (int row = 0; row < 2; ++row)
              #pragma unroll
              for (int col = 0; col < 2; ++col) {
                float ex = which ? A1[row][col] : A0[row][col], ey = 0.f;
                if (hasD && col == 1) { ey = -ex; ex = 0.f; }
                o[which*8 + row*4 + col*2 + 0] = px*ex - py*ey;
                o[which*8 + row*4 + col*2 + 1] = px*ey + py*ex;
            }
        }
    } else if (tid < 16) {
        const int pc = tid - 10;
        const bool hasS = (pc <= 2) || (pc == 4);
        float th = pool[3*pc], ph = pool[3*pc+1], la = pool[3*pc+2];
        float ct = __cosf(0.5f*th), st = __sinf(0.5f*th);
        float u[2][2][2] = {
            {{ct, 0.f},                      {-__cosf(la)*st, -__sinf(la)*st}},
            {{__cosf(ph)*st, __sinf(ph)*st}, {__cosf(ph+la)*ct, __sinf(ph+la)*ct}}};
        if (hasS) {
            #pragma unroll
            for (int row = 0; row < 2; ++row) {
                float xx = u[row][1][0], yy = u[row][1][1];
                u[row][1][0] = -yy; u[row][1][1] = xx;
            }
        }
        float* o = par + 160 + 8*pc;
        #pragma unroll
        for (int row = 0; row < 2; ++row)
          #pragma unroll
          for (int col = 0; col < 2; ++col) {
            o[row*4+col*2+0] = u[row][col][0];
            o[row*4+col*2+1] = u[row][col][1];
        }
    } else if (tid < 64) {
        par[208 + (tid - 16)] = 0.f;
    }
    __syncthreads();

    const int lane = tid & 63;
    const int sub  = lane & 15;
    PP pp{ par[lane], par[lane+64], par[lane+128], par[lane+192] };
    const int gwave = (blockIdx.x * blockDim.x + tid) >> 6;
    const int b = gwave * 4 + (lane >> 4);   // all lanes run (no divergent exit)

    const float H = 0.8660254037844386f;
    float cw[8], sw_[8];
    int rr = b;
    #pragma unroll
    for (int w = 0; w < 8; ++w) {
        int t = rr % 3; rr /= 3;
        cw[w]  = (t == 0) ? 1.f : 0.5f;
        sw_[w] = (t == 0) ? 0.f : ((t == 1) ? H : -H);
    }

    float a = ((sub & 8) ? sw_[0] : cw[0]);
    a *= (sub & 1) ? sw_[2] : cw[2];
    a *= (sub & 2) ? sw_[4] : cw[4];
    a *= (sub & 4) ? sw_[6] : cw[6];

    c32 s[16];
    float a13[4] = {cw[1]*cw[3], sw_[1]*cw[3], cw[1]*sw_[3], sw_[1]*sw_[3]};
    float a57[4] = {cw[5]*cw[7], sw_[5]*cw[7], cw[5]*sw_[7], sw_[5]*sw_[7]};
    #pragma unroll
    for (int r = 0; r < 16; ++r) s[r] = c32{ a * a13[r & 3] * a57[r >> 2], 0.f };

    conv_A<1, 8, false,  0>(s, sub, pp);
    conv_A<2, 1, true,  16>(s, sub, pp);
    conv_A<4, 2, true,  32>(s, sub, pp);
    conv_A<8, 4, true,  48>(s, sub, pp);
    conv_B<1, 1, 64>(s, sub, pp);
    conv_B<2, 2, 80>(s, sub, pp);
    conv_B<4, 4, 96>(s, sub, pp);
    pool_lanec<1, 1, 160>(s, sub, pp);
    pool_lanec<2, 2, 168>(s, sub, pp);
    pool_lanec<4, 4, 176>(s, sub, pp);
    pool_plain<8, 184>(s, pp);
    conv_RR<1, 2, false, 112>(s, pp);
    conv_RR<4, 8, true,  128>(s, pp);
    conv_RR<2, 4, false, 144>(s, pp);
    pool_regc<2, 4, 192>(s, pp);
    pool_plain<8, 200>(s, pp);

    float e3 = 0.f, e7 = 0.f;
    #pragma unroll
    for (int r = 0; r < 16; ++r) {
        float p = s[r].x*s[r].x + s[r].y*s[r].y;
        e3 += (r & 2) ? -p : p;
        e7 += (r & 8) ? -p : p;
    }
    e3 += sx<1>(e3); e3 += sx<2>(e3); e3 += sx<4>(e3); e3 += sx<8>(e3);
    e7 += sx<1>(e7); e7 += sx<2>(e7); e7 += sx<4>(e7); e7 += sx<8>(e7);

    if (sub == 0 && b < 6561) {
        // j = t0+3t1+9t2+27t3; aa = t4+3t5; bq = t6+3t7
        int j = b % 81, k = b / 81;
        int aa = k % 9, bq = k / 9;
        if (aa < 8) {
            int base = j * 72 + bq * 8 + aa;
            g_T[base]        = e3;
            g_T[5832 + base] = e7;
        } else {
            int base = 11664 + j * 12 + bq;
            g_T[base]       = e3;
            g_T[972 + base] = e7;
        }
    }
}

// ---- apply inner: one (t2,jj) row, bq-subset [B0,B1), 4 elements ----
// Trow: 9x8 main block row (global, wave-uniform); T8row: 12-float T8 row.
template<int B0, int B1>
__device__ __forceinline__ void row_dot(const float* __restrict__ Trow,
                                        const float* __restrict__ T8row,
                                        const float (&p)[4][9], const float (&q)[4][9],
                                        float (&y)[4]) {
    float t8v[B1 - B0];
    if constexpr (B0 == 0) {
        const float4 t = *reinterpret_cast<const float4*>(T8row);
        t8v[0] = t.x; t8v[1] = t.y; t8v[2] = t.z; t8v[3] = t.w;
    } else {
        const float4 t = *reinterpret_cast<const float4*>(T8row + 4);
        t8v[0] = t.x; t8v[1] = t.y; t8v[2] = t.z; t8v[3] = t.w;
        t8v[4] = T8row[8];
    }
    #pragma unroll
    for (int b = B0; b < B1; ++b) {
        const float4 T0 = *reinterpret_cast<const float4*>(Trow + b*8);
        const float4 T1 = *reinterpret_cast<const float4*>(Trow + b*8 + 4);
        const float  t8 = t8v[b - B0];
        #pragma unroll
        for (int e = 0; e < 4; ++e) {
            float sacc = T0.x * p[e][0];
            sacc = fmaf(T0.y, p[e][1], sacc);
            sacc = fmaf(T0.z, p[e][2], sacc);
            sacc = fmaf(T0.w, p[e][3], sacc);
            sacc = fmaf(T1.x, p[e][4], sacc);
            sacc = fmaf(T1.y, p[e][5], sacc);
            sacc = fmaf(T1.z, p[e][6], sacc);
            sacc = fmaf(T1.w, p[e][7], sacc);
            sacc = fmaf(t8,   p[e][8], sacc);
            y[e] = fmaf(q[e][b], sacc, y[e]);
        }
    }
}

// Lagrange cardinal triple at nodes {0, 2pi/3, -2pi/3}
__device__ __forceinline__ void lag3(float xv, float& l0, float& l1, float& l2) {
    const float A = 0.33333333333333333f;
    const float K = 0.57735026918962576f;
    float c = __cosf(xv), s = __sinf(xv);
    l0 = fmaf(2.f * A, c, A);
    float m = A * (1.f - c);
    l1 = fmaf(K, s, m);
    l2 = fmaf(-K, s, m);
}

// ---- K2: 768 threads = 12 role-waves; 4 elements/thread; T from global ----
__launch_bounds__(768, 3)
__global__ void qcnn_apply(const float* __restrict__ x,
                           const float* __restrict__ W1, const float* __restrict__ b1,
                           const float* __restrict__ W2, const float* __restrict__ b2,
                           float* __restrict__ out, int B) {
    __shared__ float Pl[3072];           // 12 partial rows x 256 elements

    const int tid  = threadIdx.x;
    const int lane = tid & 63;
    const int wave = tid >> 6;           // 0..11 = role
    const int tt   = wave & 1;           // tensor: 0 -> e3, 1 -> e7
    const int rest = wave >> 1;          // 0..5
    const int t3   = rest % 3;
    const int bh   = rest / 3;           // bq-half (alternates per t2)

    const int gbase = (blockIdx.x * 64 + lane) * 4;

    // --- per-element Lagrange basis (4 elements) ---
    float p[4][9], q[4][9], g10[4][9];
    float g3v[4], L20[4], L21[4], L22[4];
    #pragma unroll
    for (int e = 0; e < 4; ++e) {
        int idx = gbase + e; if (idx >= B) idx = B - 1;
        const float4 xa = *reinterpret_cast<const float4*>(x + idx*8);
        const float4 xb = *reinterpret_cast<const float4*>(x + idx*8 + 4);
        float l0[3], l1[3], l2[3], l3[3], l4[3], l5[3], l6[3], l7[3];
        lag3(xa.x, l0[0], l0[1], l0[2]);
        lag3(xa.y, l1[0], l1[1], l1[2]);
        lag3(xa.z, l2[0], l2[1], l2[2]);
        lag3(xa.w, l3[0], l3[1], l3[2]);
        lag3(xb.x, l4[0], l4[1], l4[2]);
        lag3(xb.y, l5[0], l5[1], l5[2]);
        lag3(xb.z, l6[0], l6[1], l6[2]);
        lag3(xb.w, l7[0], l7[1], l7[2]);
        #pragma unroll
        for (int u = 0; u < 3; ++u)
          #pragma unroll
          for (int v = 0; v < 3; ++v) {
            g10[e][u + 3*v] = l0[u] * l1[v];   // jj = t0 + 3 t1
            p[e][u + 3*v]   = l4[u] * l5[v];   // a  = t4 + 3 t5
            q[e][u + 3*v]   = l6[u] * l7[v];   // bq = t6 + 3 t7
        }
        g3v[e] = (t3 == 0) ? l3[0] : ((t3 == 1) ? l3[1] : l3[2]);
        L20[e] = l2[0]; L21[e] = l2[1]; L22[e] = l2[2];
    }

    // wave-uniform T bases, forced scalar
    const int tmBase = __builtin_amdgcn_readfirstlane(tt * 5832 + t3 * 1944);
    const int t8Base = __builtin_amdgcn_readfirstlane(11664 + tt * 972 + t3 * 324);

    // --- contraction over this role's slice ---
    float acc[4] = {0.f, 0.f, 0.f, 0.f};
    #pragma unroll
    for (int t2 = 0; t2 < 3; ++t2) {
        float u23[4];
        #pragma unroll
        for (int e = 0; e < 4; ++e) {
            float g2 = (t2 == 0) ? L20[e] : ((t2 == 1) ? L21[e] : L22[e]);
            u23[e] = g3v[e] * g2;
        }
        const float* Tt2  = g_T + tmBase + t2 * 648;
        const float* T8t2 = g_T + t8Base + t2 * 108;
        const bool takeLow = (bh == 0) ^ (t2 == 1);   // balance: 13 vs 14 rows
        #pragma unroll
        for (int jj = 0; jj < 9; ++jj) {
            float y[4] = {0.f, 0.f, 0.f, 0.f};
            if (takeLow) row_dot<0, 4>(Tt2 + jj*72, T8t2 + jj*12, p, q, y);
            else         row_dot<4, 9>(Tt2 + jj*72, T8t2 + jj*12, p, q, y);
            #pragma unroll
            for (int e = 0; e < 4; ++e)
                acc[e] = fmaf(u23[e] * g10[e][jj], y[e], acc[e]);
        }
    }

    // --- combine partials across the 12 role-waves ---
    #pragma unroll
    for (int e = 0; e < 4; ++e) Pl[wave*256 + lane*4 + e] = acc[e];
    __syncthreads();

    if (tid < 256) {
        const int elem = blockIdx.x * 256 + tid;
        if (elem < B) {
            float e3 = 0.f, e7 = 0.f;
            #pragma unroll
            for (int r = 0; r < 6; ++r) {
                e3 += Pl[(2*r)   * 256 + tid];
                e7 += Pl[(2*r+1) * 256 + tid];
            }
            float z = b2[0];
            #pragma unroll
            for (int i = 0; i < 10; ++i) {
                float h = tanh_fast(W1[2*i]*e3 + W1[2*i+1]*e7 + b1[i]);
                z += W2[i]*h;
            }
            out[elem] = 1.f / (1.f + __expf(-z));
        }
    }
}

extern "C" void kernel_launch(void* const* d_in, const int* in_sizes, int n_in,
                              void* d_out, int out_size, void* d_ws, size_t ws_size,
                              hipStream_t stream) {
    const float* x       = (const float*)d_in[0];
    const float* conv_rz = (const float*)d_in[1];
    const float* conv_ry = (const float*)d_in[2];
    const float* conv_ry2= (const float*)d_in[3];
    const float* pool    = (const float*)d_in[4];
    const float* W1      = (const float*)d_in[5];
    const float* b1      = (const float*)d_in[6];
    const float* W2      = (const float*)d_in[7];
    const float* b2      = (const float*)d_in[8];
    float* out = (float*)d_out;
    (void)d_ws; (void)ws_size;

    int B = in_sizes[0] / 8;

    qcnn_eval_grid<<<411, 256, 0, stream>>>(conv_rz, conv_ry, conv_ry2, pool);
    qcnn_apply<<<(B + 255) / 256, 768, 0, stream>>>(x, W1, b1, W2, b2, out, B);
}